// Round 4
// baseline (710.226 us; speedup 1.0000x reference)
//
#include <hip/hip_runtime.h>
#include <hip/hip_bf16.h>

#define N_NODES 100000
#define N_EDGES 1600000
#define HID 64
#define OUT_CH 32
#define NBLK_SCAN ((N_NODES + 255) / 256)   // 391

// bucketed fill parameters
#define NB 196          // ceil(100000/512) buckets of 512 consecutive dst nodes
#define EPB 8192        // edges per partition block
#define NBLK_PART ((N_EDGES + EPB - 1) / EPB)  // 196
#define SLOTS 88        // LDS slots per bucket per block (mean ~42, +7 sigma)
#define BCAP 10240      // LDS csr capacity per bucket (mean ~8192, +22 sigma)

// ---- edge_index dtype probe: int64 => all odd 32-bit words are 0 -----------
__global__ void detect_kernel(const int* __restrict__ ei, int* __restrict__ flag) {
    int i = threadIdx.x;  // 0..63
    int v = ei[2 * i + 1];
    unsigned long long ball = __ballot(v == 0);
    if (i == 0) *flag = (ball == ~0ull) ? 1 : 0;  // 1 = int64, 0 = int32
}

__device__ __forceinline__ int get_idx(const int* __restrict__ ei, int is64, long long pos) {
    return is64 ? ei[2 * pos] : ei[pos];
}

// ---- per-node counts ------------------------------------------------------
__global__ void count_kernel(const int* __restrict__ ei, const int* __restrict__ flag,
                             int* __restrict__ counts) {
    int e = blockIdx.x * blockDim.x + threadIdx.x;
    if (e >= N_EDGES) return;
    int is64 = *flag;
    int d = get_idx(ei, is64, (long long)N_EDGES + e);
    atomicAdd(&counts[d], 1);
}

__global__ void blockscan_kernel(const int* __restrict__ counts, int* __restrict__ off,
                                 int* __restrict__ bsum) {
    __shared__ int s[256];
    int tid = threadIdx.x;
    int i = blockIdx.x * 256 + tid;
    int v = (i < N_NODES) ? counts[i] : 0;
    s[tid] = v;
    __syncthreads();
    for (int d = 1; d < 256; d <<= 1) {
        int t = (tid >= d) ? s[tid - d] : 0;
        __syncthreads();
        s[tid] += t;
        __syncthreads();
    }
    if (i < N_NODES) off[i] = s[tid] - v;  // exclusive within block
    if (tid == 255) bsum[blockIdx.x] = s[255];
}

__global__ void topscan_kernel(int* __restrict__ bsum) {
    __shared__ int s[512];
    int tid = threadIdx.x;
    int v = (tid < NBLK_SCAN) ? bsum[tid] : 0;
    s[tid] = v;
    __syncthreads();
    for (int d = 1; d < 512; d <<= 1) {
        int t = (tid >= d) ? s[tid - d] : 0;
        __syncthreads();
        s[tid] += t;
        __syncthreads();
    }
    if (tid < NBLK_SCAN) bsum[tid] = s[tid] - v;  // exclusive block offsets
}

__global__ void addback_kernel(int* __restrict__ off, const int* __restrict__ bsum) {
    int i = blockIdx.x * 256 + threadIdx.x;
    if (i < N_NODES) off[i] = off[i] + bsum[i >> 8];
    if (i == 0) off[N_NODES] = N_EDGES;
}

// ---- bucket cursors: gcur[b] = off[b*512] ---------------------------------
__global__ void bucket_init_kernel(const int* __restrict__ off, int* __restrict__ gcur) {
    int t = threadIdx.x;
    if (t < NB) gcur[t] = off[t << 9];
}

// ---- phase 1: partition edges into dst buckets (LDS-staged, chunked flush) -
// record = (dst&511)<<17 | src   (src < 2^17)
__global__ void __launch_bounds__(256) partition_kernel(
        const int* __restrict__ ei, const int* __restrict__ flag,
        int* __restrict__ gcur, int* __restrict__ bkt) {
    __shared__ int lcount[NB];
    __shared__ int lbuf[NB * SLOTS];
    int tid = threadIdx.x;
    for (int i = tid; i < NB; i += 256) lcount[i] = 0;
    __syncthreads();
    int is64 = *flag;
    int e0 = blockIdx.x * EPB;
    int e1 = min(e0 + EPB, N_EDGES);
    for (int e = e0 + tid; e < e1; e += 256) {
        int s = get_idx(ei, is64, e);
        int d = get_idx(ei, is64, (long long)N_EDGES + e);
        int val = ((d & 511) << 17) | s;
        int bk = d >> 9;
        int c = atomicAdd(&lcount[bk], 1);
        if (c < SLOTS) {
            lbuf[bk * SLOTS + c] = val;
        } else {  // rare overflow: direct global scatter (correct, slow path)
            int p = atomicAdd(&gcur[bk], 1);
            bkt[p] = val;
        }
    }
    __syncthreads();
    int wid = tid >> 6, lane = tid & 63;
    for (int bk = wid; bk < NB; bk += 4) {
        int cnt = min(lcount[bk], SLOTS);
        int base;
        if (lane == 0) base = atomicAdd(&gcur[bk], cnt);
        base = __shfl(base, 0);
        for (int i = lane; i < cnt; i += 64) bkt[base + i] = lbuf[bk * SLOTS + i];
    }
}

// ---- phase 2: per-bucket csr build in LDS, coalesced flush ----------------
__global__ void __launch_bounds__(256) bucket_fill_kernel(
        const int* __restrict__ off, const int* __restrict__ bkt,
        int* __restrict__ csr) {
    __shared__ int lcur[512];
    __shared__ int scsr[BCAP];
    int b = blockIdx.x;
    int tid = threadIdx.x;
    int n0 = b << 9;
    int n1 = min(n0 + 512, N_NODES);
    int nn = n1 - n0;
    int ebase = off[n0];
    int m = off[n1] - ebase;
    for (int i = tid; i < nn; i += 256) lcur[i] = off[n0 + i] - ebase;
    __syncthreads();
    bool fit = (m <= BCAP);
    for (int e = tid; e < m; e += 256) {
        int val = bkt[ebase + e];
        int dl = val >> 17;
        int s = val & 0x1FFFF;
        int p = atomicAdd(&lcur[dl], 1);
        if (fit) scsr[p] = s;
        else csr[ebase + p] = s;  // fallback, never expected
    }
    __syncthreads();
    if (fit)
        for (int e = tid; e < m; e += 256) csr[ebase + e] = scsr[e];
}

// ---- gather-aggregate: one wave per node, lane = channel; inv_deg folded --
__global__ void __launch_bounds__(256) gather_kernel(
        const float* __restrict__ h, const int* __restrict__ off,
        const int* __restrict__ csr, float* __restrict__ agg) {
    int node = blockIdx.x * 4 + (threadIdx.x >> 6);
    if (node >= N_NODES) return;
    int o = threadIdx.x & 63;
    int off0 = off[node], off1 = off[node + 1];
    float acc = 0.f;
    int e = off0;
    int end4 = off0 + ((off1 - off0) & ~3);
    for (; e < end4; e += 4) {
        int s0 = csr[e], s1 = csr[e + 1], s2 = csr[e + 2], s3 = csr[e + 3];
        float v0 = h[(size_t)s0 * HID + o];
        float v1 = h[(size_t)s1 * HID + o];
        float v2 = h[(size_t)s2 * HID + o];
        float v3 = h[(size_t)s3 * HID + o];
        acc += v0 + v1 + v2 + v3;
    }
    for (; e < off1; ++e) acc += h[(size_t)csr[e] * HID + o];
    float inv = 1.f / fmaxf((float)(off1 - off0), 1.f);
    agg[(size_t)node * HID + o] = acc * inv;
}

// ---- layer GEMM: out = relu(agg@Wl + h@Wr + b), 64-node LDS tile ----------
#define LT 68
__global__ void __launch_bounds__(256) layer_kernel(
        const float* __restrict__ agg, const float* __restrict__ h,
        const float* __restrict__ Wl, const float* __restrict__ Wr,
        const float* __restrict__ bias, float* __restrict__ out) {
    __shared__ float sWl[HID * HID];
    __shared__ float sWr[HID * HID];
    __shared__ float sAT[HID * LT];
    __shared__ float sHT[HID * LT];
    __shared__ float sb[HID];
    int tid = threadIdx.x;
    for (int i = tid; i < HID * HID; i += 256) {
        sWl[i] = Wl[i];
        sWr[i] = Wr[i];
    }
    if (tid < HID) sb[tid] = bias[tid];

    int node0 = blockIdx.x * 64;
    int rr = tid >> 4;           // 0..15
    int cc = (tid & 15) << 2;    // 0,4,...,60
#pragma unroll
    for (int p = 0; p < 4; ++p) {
        int r = rr + p * 16;
        int n = node0 + r;
        float4 a, hh;
        if (n < N_NODES) {
            a = *(const float4*)(agg + (size_t)n * HID + cc);
            hh = *(const float4*)(h + (size_t)n * HID + cc);
        } else {
            a = make_float4(0, 0, 0, 0);
            hh = make_float4(0, 0, 0, 0);
        }
        sAT[(cc + 0) * LT + r] = a.x;  sAT[(cc + 1) * LT + r] = a.y;
        sAT[(cc + 2) * LT + r] = a.z;  sAT[(cc + 3) * LT + r] = a.w;
        sHT[(cc + 0) * LT + r] = hh.x; sHT[(cc + 1) * LT + r] = hh.y;
        sHT[(cc + 2) * LT + r] = hh.z; sHT[(cc + 3) * LT + r] = hh.w;
    }
    __syncthreads();

    int c0 = (tid & 15) << 2;
    int n0 = (tid >> 4) << 2;
    float acc[4][4];
#pragma unroll
    for (int i = 0; i < 4; ++i)
#pragma unroll
        for (int j = 0; j < 4; ++j) acc[i][j] = sb[c0 + j];

#pragma unroll 8
    for (int k = 0; k < HID; ++k) {
        float4 wl = *(const float4*)&sWl[k * HID + c0];
        float4 wr = *(const float4*)&sWr[k * HID + c0];
        float4 a4 = *(const float4*)&sAT[k * LT + n0];
        float4 h4 = *(const float4*)&sHT[k * LT + n0];
        const float* ap = (const float*)&a4;
        const float* hp = (const float*)&h4;
        const float* wlp = (const float*)&wl;
        const float* wrp = (const float*)&wr;
#pragma unroll
        for (int i = 0; i < 4; ++i)
#pragma unroll
            for (int j = 0; j < 4; ++j)
                acc[i][j] += ap[i] * wlp[j] + hp[i] * wrp[j];
    }

#pragma unroll
    for (int i = 0; i < 4; ++i) {
        int n = node0 + n0 + i;
        if (n < N_NODES) {
            float4 o4;
            o4.x = fmaxf(acc[i][0], 0.f);
            o4.y = fmaxf(acc[i][1], 0.f);
            o4.z = fmaxf(acc[i][2], 0.f);
            o4.w = fmaxf(acc[i][3], 0.f);
            *(float4*)(out + (size_t)n * HID + c0) = o4;
        }
    }
}

// ---- final head: out = h @ Wlin + blin (fp32 out) -------------------------
__global__ void __launch_bounds__(256) final_kernel(
        const float* __restrict__ h, const float* __restrict__ W,
        const float* __restrict__ b, float* __restrict__ out) {
    __shared__ float sW[HID * OUT_CH];
    __shared__ float sb[OUT_CH];
    int tid = threadIdx.x;
    for (int i = tid; i < HID * OUT_CH; i += 256) sW[i] = W[i];
    if (tid < OUT_CH) sb[tid] = b[tid];
    __syncthreads();

    int node = blockIdx.x * 8 + (tid >> 5);
    if (node >= N_NODES) return;
    int o = tid & 31;
    const float* hr = h + (size_t)node * HID;
    float acc = sb[o];
#pragma unroll 8
    for (int k = 0; k < HID; k++) acc += hr[k] * sW[k * OUT_CH + o];
    out[(size_t)node * OUT_CH + o] = acc;
}

extern "C" void kernel_launch(void* const* d_in, const int* in_sizes, int n_in,
                              void* d_out, int out_size, void* d_ws, size_t ws_size,
                              hipStream_t stream) {
    const float* x    = (const float*)d_in[0];
    const int*   ei   = (const int*)d_in[1];
    const float* Wl1  = (const float*)d_in[2];
    const float* Wr1  = (const float*)d_in[3];
    const float* b1   = (const float*)d_in[4];
    const float* Wl2  = (const float*)d_in[5];
    const float* Wr2  = (const float*)d_in[6];
    const float* b2   = (const float*)d_in[7];
    const float* Wl3  = (const float*)d_in[8];
    const float* Wr3  = (const float*)d_in[9];
    const float* b3   = (const float*)d_in[10];
    const float* Wlin = (const float*)d_in[11];
    const float* blin = (const float*)d_in[12];
    float* out = (float*)d_out;

    // workspace layout (4-byte elements), ~58.4 MB total
    int* ip     = (int*)d_ws;
    int* flag   = ip;                    // 128
    int* off    = flag + 128;            // 100001 (reserve 100224)
    int* counts = off + 100224;          // 100096
    int* bsum   = counts + 100096;       // 512
    int* gcur   = bsum + 512;            // 256
    int* csr    = gcur + 256;            // 1600000
    float* agg  = (float*)(csr + N_EDGES);        // 6.4M floats
    float* feat = agg + (size_t)N_NODES * HID;    // 6.4M floats
    int* bkt    = (int*)agg;   // bucketed records alias agg (dead before gather)

    const int EB = (N_EDGES + 255) / 256;        // 6250
    const int GATHER_BLOCKS = (N_NODES + 3) / 4; // 25000
    const int LAYER_BLOCKS = (N_NODES + 63) / 64;// 1563
    const int FINAL_BLOCKS = (N_NODES + 7) / 8;  // 12500

    // CSR build
    detect_kernel<<<1, 64, 0, stream>>>(ei, flag);
    hipMemsetAsync(counts, 0, (size_t)N_NODES * 4, stream);
    count_kernel<<<EB, 256, 0, stream>>>(ei, flag, counts);
    blockscan_kernel<<<NBLK_SCAN, 256, 0, stream>>>(counts, off, bsum);
    topscan_kernel<<<1, 512, 0, stream>>>(bsum);
    addback_kernel<<<NBLK_SCAN, 256, 0, stream>>>(off, bsum);
    bucket_init_kernel<<<1, 256, 0, stream>>>(off, gcur);
    partition_kernel<<<NBLK_PART, 256, 0, stream>>>(ei, flag, gcur, bkt);
    bucket_fill_kernel<<<NB, 256, 0, stream>>>(off, bkt, csr);

    // layer 1: x -> feat
    gather_kernel<<<GATHER_BLOCKS, 256, 0, stream>>>(x, off, csr, agg);
    layer_kernel<<<LAYER_BLOCKS, 256, 0, stream>>>(agg, x, Wl1, Wr1, b1, feat);

    // layer 2: feat -> feat (in-place safe: tile staged in LDS before write)
    gather_kernel<<<GATHER_BLOCKS, 256, 0, stream>>>(feat, off, csr, agg);
    layer_kernel<<<LAYER_BLOCKS, 256, 0, stream>>>(agg, feat, Wl2, Wr2, b2, feat);

    // layer 3
    gather_kernel<<<GATHER_BLOCKS, 256, 0, stream>>>(feat, off, csr, agg);
    layer_kernel<<<LAYER_BLOCKS, 256, 0, stream>>>(agg, feat, Wl3, Wr3, b3, feat);

    // head
    final_kernel<<<FINAL_BLOCKS, 256, 0, stream>>>(feat, Wlin, blin, out);
}